// Round 7
// baseline (169.088 us; speedup 1.0000x reference)
//
#include <hip/hip_runtime.h>
#include <hip/hip_bf16.h>

// SpectralConv2d (FNO): B=8, C_IN=C_OUT=32, H=W=256, modes 32x32 (low kx) + 32x32 (high kx), ky 0..31.
// R6: h-DFTs as bf16 MFMA GEMMs (split-real twiddle tables Tm/Th). 165.1 us.
// R7: k_fftA h-half split (grid 512, K=128 partial-ZZ, LDS 51.2KB -> 2 blocks/CU);
//     k_mix sums partials and writes Zmix as bf16 complex (bit-exact: fftC rounded it anyway);
//     k_fftC stages from bf16 Zmix.  ~123us of dur_us is fixed harness poison-fill overhead.

#define BD 256

typedef __attribute__((ext_vector_type(8))) short bf16x8;
typedef __attribute__((ext_vector_type(4))) float f32x4;

__device__ inline unsigned short f2bf(float f) {
    union { float f; unsigned u; } v; v.f = f;
    unsigned r = v.u + 0x7FFF + ((v.u >> 16) & 1);   // RNE
    return (unsigned short)(r >> 16);
}

// Merged setup:
//   b 0        -> tw[t] = (cos,sin)(2pi t/256)
//   b 1..128   -> BmA [64][256] (n=2ky+c: cos/-sin), BmC [256][64] (k=2ky+c: cos/-sin)
//   b 129..256 -> Tm [128][256]: Tm[2j+c][h] = cos/-sin(2pi kxj h/256), kxj = j<32? j : j+192
//   b 257..384 -> Th [256][128]: Th[h][2m+c] = cos/-sin(2pi kxm h/256), kxm = m<32? m : m+192
//   b 385..896 -> wpack transpose: wpack[(m*32+ky)*1024 + io] = w[io][m'*32+ky] * scale
__global__ void k_setup(float2* __restrict__ tw,
                        unsigned short* __restrict__ BmA, unsigned short* __restrict__ BmC,
                        unsigned short* __restrict__ Tm, unsigned short* __restrict__ Th,
                        const float* __restrict__ w1r, const float* __restrict__ w1i,
                        const float* __restrict__ w2r, const float* __restrict__ w2i,
                        float2* __restrict__ wpack) {
    __shared__ float Tr[64][65];
    __shared__ float Ti[64][65];
    int b = blockIdx.x, t = threadIdx.x;
    if (b == 0) {
        double th = 6.283185307179586476925286766559 * (double)t / 256.0;
        tw[t] = make_float2((float)cos(th), (float)sin(th));
    } else if (b <= 128) {
        int idx = (b - 1) * BD + t;    // 0..32767
        if (idx < 16384) {
            int w = idx & 255, n = idx >> 8;
            int ky = n >> 1, c = n & 1;
            double th = 6.283185307179586476925286766559 * (double)((ky * w) & 255) / 256.0;
            BmA[idx] = f2bf(c ? (float)(-sin(th)) : (float)cos(th));
        } else {
            int j = idx - 16384;
            int k = j & 63, w = j >> 6;
            int ky = k >> 1, c = k & 1;
            double th = 6.283185307179586476925286766559 * (double)((ky * w) & 255) / 256.0;
            BmC[j] = f2bf(c ? (float)(-sin(th)) : (float)cos(th));
        }
    } else if (b <= 256) {
        int idx = (b - 129) * BD + t;  // 0..32767, Tm[n2*256+h]
        int h = idx & 255, n2 = idx >> 8;
        int j = n2 >> 1, c = n2 & 1;
        int kx = (j < 32) ? j : j + 192;
        double th = 6.283185307179586476925286766559 * (double)((kx * h) & 255) / 256.0;
        Tm[idx] = f2bf(c ? (float)(-sin(th)) : (float)cos(th));
    } else if (b <= 384) {
        int idx = (b - 257) * BD + t;  // 0..32767, Th[h*128+k2]
        int k2 = idx & 127, h = idx >> 7;
        int m = k2 >> 1, c = k2 & 1;
        int kx = (m < 32) ? m : m + 192;
        double th = 6.283185307179586476925286766559 * (double)((kx * h) & 255) / 256.0;
        Th[idx] = f2bf(c ? (float)(-sin(th)) : (float)cos(th));
    } else {
        int blk = b - 385;              // 0..511
        int half = blk >> 8;            // 0: w1 (m<32), 1: w2 (m>=32)
        int tile = blk & 255;
        int tr = tile >> 4, tc = tile & 15;     // io-tile, cm-tile
        int io0 = tr * 64, cm0 = tc * 64;
        const float* wr = half ? w2r : w1r;
        const float* wi = half ? w2i : w1i;
        int rr = t >> 2, c0 = (t & 3) * 16;
        {   // load 64x64 tile, coalesced
            const float4* srcr = (const float4*)(wr + (long)(io0 + rr) * 1024 + cm0 + c0);
            const float4* srci = (const float4*)(wi + (long)(io0 + rr) * 1024 + cm0 + c0);
#pragma unroll
            for (int p = 0; p < 4; ++p) {
                float4 vr = srcr[p], vi = srci[p];
                int cc = c0 + p * 4;
                Tr[rr][cc + 0] = vr.x; Tr[rr][cc + 1] = vr.y; Tr[rr][cc + 2] = vr.z; Tr[rr][cc + 3] = vr.w;
                Ti[rr][cc + 0] = vi.x; Ti[rr][cc + 1] = vi.y; Ti[rr][cc + 2] = vi.z; Ti[rr][cc + 3] = vi.w;
            }
        }
        __syncthreads();
        {   // write transposed, coalesced
            int cm = cm0 + rr;
            int ky = cm & 31;
            float s = (ky == 0 ? 1.0f : 2.0f) * (1.0f / 65536.0f);
            float2* dst = wpack + ((long)(half * 1024 + cm)) * 1024 + io0 + c0;
#pragma unroll
            for (int k = 0; k < 16; ++k)
                dst[k] = make_float2(Tr[c0 + k][rr] * s, Ti[c0 + k][rr] * s);
        }
    }
}

// Fused A (all-MFMA, h-half split): block = (bi, hh2). 2 chunks of 64 h-rows:
//   stage x->As bf16; MFMA Y = x * BmA^T; write Y bf16 transposed -> Ybt[64 cols][128 h-local].
// Then MFMA partial ZZ[128][64] = Tm[128][K=128 @ hh2*128] * Ybt; combine -> partial Z.
__global__ __launch_bounds__(512) void k_fftA(const float* __restrict__ x,
                                              const unsigned short* __restrict__ BmA,
                                              const unsigned short* __restrict__ Tm,
                                              float2* __restrict__ Z) {
    __shared__ __align__(16) unsigned short Ybt[64 * 136];   // 17408 B [col n][h-local]
    __shared__ __align__(16) char buf[64 * 264 * 2];         // 33792 B: As [64][264] / ZZs [128][65] f32
    unsigned short* As = (unsigned short*)buf;
    float* ZZs = (float*)buf;
    int t = threadIdx.x, bi = blockIdx.x >> 1, hh2 = blockIdx.x & 1;
    int wv = t >> 6, lane = t & 63, lm = lane & 15, quad = lane >> 4;
    int nst = (wv >> 1) * 16, mh = wv & 1;
    // preload W-DFT B-fragments from global (L2-resident BmA)
    bf16x8 bfr[8];
#pragma unroll
    for (int kk = 0; kk < 8; ++kk)
        bfr[kk] = *(const bf16x8*)&BmA[(nst + lm) * 256 + kk * 32 + quad * 8];
    int sr = t >> 3, sc = (t & 7) * 32;
    for (int c = 0; c < 2; ++c) {
        {   // stage x chunk (64 rows x 256) -> As bf16
            const float* xp = x + ((long)bi * 256 + hh2 * 128 + c * 64 + sr) * 256 + sc;
            unsigned short* dst = &As[sr * 264 + sc];
#pragma unroll
            for (int j = 0; j < 8; ++j) {
                float4 v = *(const float4*)(xp + j * 4);
                ushort4 bq;
                bq.x = f2bf(v.x); bq.y = f2bf(v.y); bq.z = f2bf(v.z); bq.w = f2bf(v.w);
                *(ushort4*)(dst + j * 4) = bq;
            }
        }
        __syncthreads();
        f32x4 acc0 = {}, acc1 = {};
#pragma unroll
        for (int kk = 0; kk < 8; ++kk) {
            bf16x8 af0 = *(const bf16x8*)&As[(mh * 32 + lm) * 264 + kk * 32 + quad * 8];
            bf16x8 af1 = *(const bf16x8*)&As[(mh * 32 + 16 + lm) * 264 + kk * 32 + quad * 8];
            acc0 = __builtin_amdgcn_mfma_f32_16x16x32_bf16(af0, bfr[kk], acc0, 0, 0, 0);
            acc1 = __builtin_amdgcn_mfma_f32_16x16x32_bf16(af1, bfr[kk], acc1, 0, 0, 0);
        }
        {   // Y -> Ybt bf16 (transposed): col = nst+lm, h-local = c*64 + mh*32 + quad*4 (+16 for acc1)
            ushort4 w0, w1;
            w0.x = f2bf(acc0[0]); w0.y = f2bf(acc0[1]); w0.z = f2bf(acc0[2]); w0.w = f2bf(acc0[3]);
            w1.x = f2bf(acc1[0]); w1.y = f2bf(acc1[1]); w1.z = f2bf(acc1[2]); w1.w = f2bf(acc1[3]);
            int base = (nst + lm) * 136 + c * 64 + mh * 32 + quad * 4;
            *(ushort4*)&Ybt[base] = w0;
            *(ushort4*)&Ybt[base + 16] = w1;
        }
        __syncthreads();
    }
    // Partial ZZ[n2][col] = sum_{h in half} Tm[n2][hh2*128+h] * Ybt[col][h].  M=128, N=64, K=128.
    bf16x8 afr[4];
#pragma unroll
    for (int kk = 0; kk < 4; ++kk)
        afr[kk] = *(const bf16x8*)&Tm[(wv * 16 + lm) * 256 + hh2 * 128 + kk * 32 + quad * 8];
    f32x4 az[4] = {};
#pragma unroll
    for (int kk = 0; kk < 4; ++kk)
#pragma unroll
        for (int nt = 0; nt < 4; ++nt) {
            bf16x8 bf = *(const bf16x8*)&Ybt[(nt * 16 + lm) * 136 + kk * 32 + quad * 8];
            az[nt] = __builtin_amdgcn_mfma_f32_16x16x32_bf16(afr[kk], bf, az[nt], 0, 0, 0);
        }
#pragma unroll
    for (int nt = 0; nt < 4; ++nt)
#pragma unroll
        for (int r = 0; r < 4; ++r)
            ZZs[(wv * 16 + quad * 4 + r) * 65 + nt * 16 + lm] = az[nt][r];
    __syncthreads();
    // Combine: Zr = ZZ[2m][2ky] - ZZ[2m+1][2ky+1]; Zi = ZZ[2m][2ky+1] + ZZ[2m+1][2ky]
#pragma unroll
    for (int p = 0; p < 4; ++p) {
        int cid = p * 512 + t;
        int m = cid >> 5, ky = cid & 31;
        float zr = ZZs[(2 * m) * 65 + 2 * ky]     - ZZs[(2 * m + 1) * 65 + 2 * ky + 1];
        float zi = ZZs[(2 * m) * 65 + 2 * ky + 1] + ZZs[(2 * m + 1) * 65 + 2 * ky];
        Z[(long)(hh2 * 256 + bi) * 2048 + cid] = make_float2(zr, zi);
    }
}

// B: Zmix[b][o][m][ky] = sum_i (Z0+Z1)[b][i][m][ky] * Wpack[m][ky][i][o].  Output bf16 complex.
__global__ void k_mix(const float2* __restrict__ Z, const float2* __restrict__ wpack,
                      unsigned* __restrict__ Zmixb) {
    __shared__ float2 Ws[4][1024];   // 32 KB
    __shared__ float2 Zs[256][4];    // 8 KB  [bi][kk]
    __shared__ float2 Os[256][4];    // 8 KB  [bo][kk]
    int t = threadIdx.x;
    int mk0 = blockIdx.x * 4;
    {
        const float4* src = (const float4*)(wpack + (long)mk0 * 1024);
        float4* dst = (float4*)&Ws[0][0];
        for (int j = t; j < 2048; j += BD) dst[j] = src[j];
    }
    for (int j = t; j < 512; j += BD) {   // stage Z = Z0 + Z1 (h-half partials)
        int bi = j >> 1, p = j & 1;
        float4 a = *(const float4*)&Z[(long)bi * 2048 + mk0 + p * 2];
        float4 b = *(const float4*)&Z[(long)(256 + bi) * 2048 + mk0 + p * 2];
        float4 s;
        s.x = a.x + b.x; s.y = a.y + b.y; s.z = a.z + b.z; s.w = a.w + b.w;
        *(float4*)&Zs[bi][p * 2] = s;
    }
    __syncthreads();
    int o = t & 31, kk = (t >> 5) & 3, bh = t >> 7;
    float ar[4], ai[4];
#pragma unroll
    for (int j = 0; j < 4; ++j) { ar[j] = 0.f; ai[j] = 0.f; }
    for (int i = 0; i < 32; ++i) {
        float2 w = Ws[kk][i * 32 + o];
#pragma unroll
        for (int j = 0; j < 4; ++j) {
            float2 z = Zs[(bh * 4 + j) * 32 + i][kk];   // wave-broadcast
            ar[j] = fmaf(z.x, w.x, fmaf(-z.y, w.y, ar[j]));
            ai[j] = fmaf(z.x, w.y, fmaf( z.y, w.x, ai[j]));
        }
    }
#pragma unroll
    for (int j = 0; j < 4; ++j)
        Os[(bh * 4 + j) * 32 + o][kk] = make_float2(ar[j], ai[j]);
    __syncthreads();
    for (int j = t; j < 512; j += BD) {   // write bf16 complex: 2 complex = uint2 per j
        int row = j >> 1, p = j & 1;
        float2 a = Os[row][p * 2], b2 = Os[row][p * 2 + 1];
        uint2 u;
        u.x = (unsigned)f2bf(a.x)  | ((unsigned)f2bf(a.y)  << 16);
        u.y = (unsigned)f2bf(b2.x) | ((unsigned)f2bf(b2.y) << 16);
        *(uint2*)&Zmixb[(long)row * 2048 + mk0 + p * 2] = u;
    }
}

// Fused C (all-MFMA): block = (bo, h-half), 512 threads (8 waves).
// Phase 1: Bz[2ky+cc][2m+c] bf16 from bf16 Zmix; MFMA G[128 h1][64] = Th * Bz -> Gs bf16.
// Phase 2: C2 MFMA out[128 h][256 w] = Gs * BmC^T + bias.
__global__ __launch_bounds__(512) void k_fftC(const unsigned* __restrict__ Zmixb,
                                              const unsigned short* __restrict__ Th,
                                              const unsigned short* __restrict__ BmC,
                                              const float* __restrict__ bias,
                                              float* __restrict__ out) {
    __shared__ __align__(16) unsigned short Gs[128 * 72];   // 18432 B
    __shared__ __align__(16) char buf[128 * 72 * 2];        // 18432 B: Bz [64][136] / Bsh [128][72]
    unsigned short* Bz = (unsigned short*)buf;
    unsigned short* Bsh = (unsigned short*)buf;
    int t = threadIdx.x;
    int bo = blockIdx.x >> 1, hb = blockIdx.x & 1;
    {   // stage Bz: Bz[2ky][2m]=Zr, Bz[2ky][2m+1]=Zi, Bz[2ky+1][2m]=Zi, Bz[2ky+1][2m+1]=-Zr
#pragma unroll
        for (int p = 0; p < 4; ++p) {
            int cid = p * 512 + t;
            int m = cid >> 5, ky = cid & 31;
            unsigned z = Zmixb[(long)bo * 2048 + cid];
            unsigned short zr = (unsigned short)z;
            unsigned short zi = (unsigned short)(z >> 16);
            unsigned short nzr = zr ^ 0x8000;
            Bz[(2 * ky) * 136 + 2 * m]         = zr;
            Bz[(2 * ky) * 136 + 2 * m + 1]     = zi;
            Bz[(2 * ky + 1) * 136 + 2 * m]     = zi;
            Bz[(2 * ky + 1) * 136 + 2 * m + 1] = nzr;
        }
    }
    __syncthreads();
    int wv = t >> 6, lane = t & 63, lm = lane & 15, quad = lane >> 4;
    {   // GEMM1: G[h1][col] = sum_k2 Th[h][k2] * Bz[col][k2].  M=128, N=64, K=128.
        bf16x8 afr[4];
#pragma unroll
        for (int kk = 0; kk < 4; ++kk)
            afr[kk] = *(const bf16x8*)&Th[(hb * 128 + wv * 16 + lm) * 128 + kk * 32 + quad * 8];
        f32x4 ag[4] = {};
#pragma unroll
        for (int kk = 0; kk < 4; ++kk)
#pragma unroll
            for (int nt = 0; nt < 4; ++nt) {
                bf16x8 bf = *(const bf16x8*)&Bz[(nt * 16 + lm) * 136 + kk * 32 + quad * 8];
                ag[nt] = __builtin_amdgcn_mfma_f32_16x16x32_bf16(afr[kk], bf, ag[nt], 0, 0, 0);
            }
#pragma unroll
        for (int nt = 0; nt < 4; ++nt)
#pragma unroll
            for (int r = 0; r < 4; ++r)
                Gs[(wv * 16 + quad * 4 + r) * 72 + nt * 16 + lm] = f2bf(ag[nt][r]);
    }
    __syncthreads();   // Gs complete; Bz dead
    // C2: 8 waves x 16 rows; per phase p: N-half of 128 cols
    bf16x8 a0 = *(const bf16x8*)&Gs[(wv * 16 + lm) * 72 + quad * 8];
    bf16x8 a1 = *(const bf16x8*)&Gs[(wv * 16 + lm) * 72 + 32 + quad * 8];
    float bv = bias[bo & 31];
    long rowbase = (long)bo * 256 + hb * 128 + wv * 16;
    for (int p = 0; p < 2; ++p) {
        if (p) __syncthreads();   // all waves done reading Bsh phase 0
        {   // stage BmC half: rows p*128..p*128+128; 512 thr x 2 uint4 (16 shorts)
            int w = t >> 2, k0 = (t & 3) * 16;
            const uint4* src = (const uint4*)(BmC + (p * 128 + w) * 64 + k0);
            *(uint4*)&Bsh[w * 72 + k0]     = src[0];
            *(uint4*)&Bsh[w * 72 + k0 + 8] = src[1];
        }
        __syncthreads();
        f32x4 acc[8] = {};
#pragma unroll
        for (int nt = 0; nt < 8; ++nt) {
            bf16x8 b0 = *(const bf16x8*)&Bsh[(nt * 16 + lm) * 72 + quad * 8];
            bf16x8 b1 = *(const bf16x8*)&Bsh[(nt * 16 + lm) * 72 + 32 + quad * 8];
            acc[nt] = __builtin_amdgcn_mfma_f32_16x16x32_bf16(a0, b0, acc[nt], 0, 0, 0);
            acc[nt] = __builtin_amdgcn_mfma_f32_16x16x32_bf16(a1, b1, acc[nt], 0, 0, 0);
        }
#pragma unroll
        for (int nt = 0; nt < 8; ++nt)
#pragma unroll
            for (int r = 0; r < 4; ++r)
                out[(rowbase + quad * 4 + r) * 256 + p * 128 + nt * 16 + lm] = acc[nt][r] + bv;
    }
}

extern "C" void kernel_launch(void* const* d_in, const int* in_sizes, int n_in,
                              void* d_out, int out_size, void* d_ws, size_t ws_size,
                              hipStream_t stream) {
    const float* x    = (const float*)d_in[0];
    const float* w1r  = (const float*)d_in[1];
    const float* w1i  = (const float*)d_in[2];
    const float* w2r  = (const float*)d_in[3];
    const float* w2i  = (const float*)d_in[4];
    const float* bias = (const float*)d_in[5];

    char* ws = (char*)d_ws;
    float2* tw             = (float2*)(ws);                                  // 2 KB (slot 4KB)
    float2* wpack          = (float2*)(ws + 4096);                           // 16 MB
    unsigned short* BmA    = (unsigned short*)(ws + 4096 + (16l << 20));     // 32 KB
    unsigned short* BmC    = BmA + 64 * 256;                                 // 32 KB
    unsigned short* Tm     = (unsigned short*)(ws + 4096 + (16l << 20) + 65536);       // 64 KB
    unsigned short* Th     = Tm + 128 * 256;                                           // 64 KB
    float2* Z              = (float2*)(ws + 4096 + (16l << 20) + 65536 + 131072);      // 8 MB (2 partials)
    unsigned* Zmixb        = (unsigned*)((char*)Z + (8l << 20));             // 2 MB (bf16 complex)
    float* out             = (float*)d_out;

    k_setup <<<897, BD, 0, stream>>>(tw, BmA, BmC, Tm, Th, w1r, w1i, w2r, w2i, wpack);
    k_fftA  <<<512, 512, 0, stream>>>(x, BmA, Tm, Z);
    k_mix   <<<512, BD, 0, stream>>>(Z, wpack, Zmixb);
    k_fftC  <<<512, 512, 0, stream>>>(Zmixb, Th, BmC, bias, out);
}

// Round 8
// 160.174 us; speedup vs baseline: 1.0556x; 1.0556x over previous
//
#include <hip/hip_runtime.h>
#include <hip/hip_bf16.h>

// SpectralConv2d (FNO): B=8, C_IN=C_OUT=32, H=W=256, modes 32x32 (low kx) + 32x32 (high kx), ky 0..31.
// R6: h-DFTs as bf16 MFMA GEMMs (split-real twiddle tables Tm/Th). 165.1 us.
// R7 post-mortem: fftA h-half split regressed (+4us: doubled Z traffic, no occupancy gain) -> reverted.
// R8: R6 fftA + bf16 Zmix (bit-exact, kept from R7) + bf16 wpack (halves setup-write/mix-read).

#define BD 256

typedef __attribute__((ext_vector_type(8))) short bf16x8;
typedef __attribute__((ext_vector_type(4))) float f32x4;

__device__ inline unsigned short f2bf(float f) {
    union { float f; unsigned u; } v; v.f = f;
    unsigned r = v.u + 0x7FFF + ((v.u >> 16) & 1);   // RNE
    return (unsigned short)(r >> 16);
}

__device__ inline float bf2f(unsigned short b) {
    union { unsigned u; float f; } v; v.u = ((unsigned)b) << 16;
    return v.f;
}

// Merged setup:
//   b 0        -> tw[t] = (cos,sin)(2pi t/256)
//   b 1..128   -> BmA [64][256] (n=2ky+c: cos/-sin), BmC [256][64] (k=2ky+c: cos/-sin)
//   b 129..256 -> Tm [128][256]: Tm[2j+c][h] = cos/-sin(2pi kxj h/256), kxj = j<32? j : j+192
//   b 257..384 -> Th [256][128]: Th[h][2m+c] = cos/-sin(2pi kxm h/256), kxm = m<32? m : m+192
//   b 385..896 -> wpack transpose (bf16 complex): wpack[(m*32+ky)*1024+io] = pack(w[io][m'*32+ky]*s)
__global__ void k_setup(float2* __restrict__ tw,
                        unsigned short* __restrict__ BmA, unsigned short* __restrict__ BmC,
                        unsigned short* __restrict__ Tm, unsigned short* __restrict__ Th,
                        const float* __restrict__ w1r, const float* __restrict__ w1i,
                        const float* __restrict__ w2r, const float* __restrict__ w2i,
                        unsigned* __restrict__ wpack) {
    __shared__ float Tr[64][65];
    __shared__ float Ti[64][65];
    int b = blockIdx.x, t = threadIdx.x;
    if (b == 0) {
        double th = 6.283185307179586476925286766559 * (double)t / 256.0;
        tw[t] = make_float2((float)cos(th), (float)sin(th));
    } else if (b <= 128) {
        int idx = (b - 1) * BD + t;    // 0..32767
        if (idx < 16384) {
            int w = idx & 255, n = idx >> 8;
            int ky = n >> 1, c = n & 1;
            double th = 6.283185307179586476925286766559 * (double)((ky * w) & 255) / 256.0;
            BmA[idx] = f2bf(c ? (float)(-sin(th)) : (float)cos(th));
        } else {
            int j = idx - 16384;
            int k = j & 63, w = j >> 6;
            int ky = k >> 1, c = k & 1;
            double th = 6.283185307179586476925286766559 * (double)((ky * w) & 255) / 256.0;
            BmC[j] = f2bf(c ? (float)(-sin(th)) : (float)cos(th));
        }
    } else if (b <= 256) {
        int idx = (b - 129) * BD + t;  // 0..32767, Tm[n2*256+h]
        int h = idx & 255, n2 = idx >> 8;
        int j = n2 >> 1, c = n2 & 1;
        int kx = (j < 32) ? j : j + 192;
        double th = 6.283185307179586476925286766559 * (double)((kx * h) & 255) / 256.0;
        Tm[idx] = f2bf(c ? (float)(-sin(th)) : (float)cos(th));
    } else if (b <= 384) {
        int idx = (b - 257) * BD + t;  // 0..32767, Th[h*128+k2]
        int k2 = idx & 127, h = idx >> 7;
        int m = k2 >> 1, c = k2 & 1;
        int kx = (m < 32) ? m : m + 192;
        double th = 6.283185307179586476925286766559 * (double)((kx * h) & 255) / 256.0;
        Th[idx] = f2bf(c ? (float)(-sin(th)) : (float)cos(th));
    } else {
        int blk = b - 385;              // 0..511
        int half = blk >> 8;            // 0: w1 (m<32), 1: w2 (m>=32)
        int tile = blk & 255;
        int tr = tile >> 4, tc = tile & 15;     // io-tile, cm-tile
        int io0 = tr * 64, cm0 = tc * 64;
        const float* wr = half ? w2r : w1r;
        const float* wi = half ? w2i : w1i;
        int rr = t >> 2, c0 = (t & 3) * 16;
        {   // load 64x64 tile, coalesced
            const float4* srcr = (const float4*)(wr + (long)(io0 + rr) * 1024 + cm0 + c0);
            const float4* srci = (const float4*)(wi + (long)(io0 + rr) * 1024 + cm0 + c0);
#pragma unroll
            for (int p = 0; p < 4; ++p) {
                float4 vr = srcr[p], vi = srci[p];
                int cc = c0 + p * 4;
                Tr[rr][cc + 0] = vr.x; Tr[rr][cc + 1] = vr.y; Tr[rr][cc + 2] = vr.z; Tr[rr][cc + 3] = vr.w;
                Ti[rr][cc + 0] = vi.x; Ti[rr][cc + 1] = vi.y; Ti[rr][cc + 2] = vi.z; Ti[rr][cc + 3] = vi.w;
            }
        }
        __syncthreads();
        {   // write transposed, coalesced, bf16 complex
            int cm = cm0 + rr;
            int ky = cm & 31;
            float s = (ky == 0 ? 1.0f : 2.0f) * (1.0f / 65536.0f);
            unsigned* dst = wpack + ((long)(half * 1024 + cm)) * 1024 + io0 + c0;
#pragma unroll
            for (int k = 0; k < 16; ++k)
                dst[k] = (unsigned)f2bf(Tr[c0 + k][rr] * s) | ((unsigned)f2bf(Ti[c0 + k][rr] * s) << 16);
        }
    }
}

// Fused A (all-MFMA, R6 structure): block = bi (b*32+c_in), 512 threads (8 waves).
// Phase 1 (4 chunks of 64 h-rows): stage x->As bf16; MFMA Y = x * BmA^T; Y bf16 -> Ybt[64][256].
// Phase 2: MFMA ZZ[128][64] = Tm[128][256] * Ybt; combine -> Z complex.
__global__ __launch_bounds__(512) void k_fftA(const float* __restrict__ x,
                                              const unsigned short* __restrict__ BmA,
                                              const unsigned short* __restrict__ Tm,
                                              float2* __restrict__ Z) {
    __shared__ __align__(16) unsigned short Ybt[64 * 264];   // 33792 B [col n][h]
    __shared__ __align__(16) char buf[64 * 264 * 2];         // 33792 B: As [64][264] / ZZs [128][65] f32
    unsigned short* As = (unsigned short*)buf;
    float* ZZs = (float*)buf;
    int t = threadIdx.x, bi = blockIdx.x;
    int wv = t >> 6, lane = t & 63, lm = lane & 15, quad = lane >> 4;
    int nst = (wv >> 1) * 16, mh = wv & 1;
    // preload W-DFT B-fragments from global (L2-resident BmA)
    bf16x8 bfr[8];
#pragma unroll
    for (int kk = 0; kk < 8; ++kk)
        bfr[kk] = *(const bf16x8*)&BmA[(nst + lm) * 256 + kk * 32 + quad * 8];
    int sr = t >> 3, sc = (t & 7) * 32;
    for (int c = 0; c < 4; ++c) {
        {   // stage x chunk (64 rows x 256) -> As bf16
            const float* xp = x + ((long)bi * 256 + c * 64 + sr) * 256 + sc;
            unsigned short* dst = &As[sr * 264 + sc];
#pragma unroll
            for (int j = 0; j < 8; ++j) {
                float4 v = *(const float4*)(xp + j * 4);
                ushort4 bq;
                bq.x = f2bf(v.x); bq.y = f2bf(v.y); bq.z = f2bf(v.z); bq.w = f2bf(v.w);
                *(ushort4*)(dst + j * 4) = bq;
            }
        }
        __syncthreads();
        f32x4 acc0 = {}, acc1 = {};
#pragma unroll
        for (int kk = 0; kk < 8; ++kk) {
            bf16x8 af0 = *(const bf16x8*)&As[(mh * 32 + lm) * 264 + kk * 32 + quad * 8];
            bf16x8 af1 = *(const bf16x8*)&As[(mh * 32 + 16 + lm) * 264 + kk * 32 + quad * 8];
            acc0 = __builtin_amdgcn_mfma_f32_16x16x32_bf16(af0, bfr[kk], acc0, 0, 0, 0);
            acc1 = __builtin_amdgcn_mfma_f32_16x16x32_bf16(af1, bfr[kk], acc1, 0, 0, 0);
        }
        {   // Y -> Ybt bf16 (transposed): col n = nst+lm, rows h = c*64 + mh*32 + quad*4 (+16)
            ushort4 w0, w1;
            w0.x = f2bf(acc0[0]); w0.y = f2bf(acc0[1]); w0.z = f2bf(acc0[2]); w0.w = f2bf(acc0[3]);
            w1.x = f2bf(acc1[0]); w1.y = f2bf(acc1[1]); w1.z = f2bf(acc1[2]); w1.w = f2bf(acc1[3]);
            int base = (nst + lm) * 264 + c * 64 + mh * 32 + quad * 4;
            *(ushort4*)&Ybt[base] = w0;
            *(ushort4*)&Ybt[base + 16] = w1;
        }
        __syncthreads();
    }
    // Phase 2: ZZ[n2][col] = sum_h Tm[n2][h] * Ybt[col][h].  M=128 (wave: wv*16), N=64, K=256.
    bf16x8 afr[8];
#pragma unroll
    for (int kk = 0; kk < 8; ++kk)
        afr[kk] = *(const bf16x8*)&Tm[(wv * 16 + lm) * 256 + kk * 32 + quad * 8];
    f32x4 az[4] = {};
#pragma unroll
    for (int kk = 0; kk < 8; ++kk)
#pragma unroll
        for (int nt = 0; nt < 4; ++nt) {
            bf16x8 bf = *(const bf16x8*)&Ybt[(nt * 16 + lm) * 264 + kk * 32 + quad * 8];
            az[nt] = __builtin_amdgcn_mfma_f32_16x16x32_bf16(afr[kk], bf, az[nt], 0, 0, 0);
        }
#pragma unroll
    for (int nt = 0; nt < 4; ++nt)
#pragma unroll
        for (int r = 0; r < 4; ++r)
            ZZs[(wv * 16 + quad * 4 + r) * 65 + nt * 16 + lm] = az[nt][r];
    __syncthreads();
    // Combine: Zr = ZZ[2m][2ky] - ZZ[2m+1][2ky+1]; Zi = ZZ[2m][2ky+1] + ZZ[2m+1][2ky]
#pragma unroll
    for (int p = 0; p < 4; ++p) {
        int cid = p * 512 + t;
        int m = cid >> 5, ky = cid & 31;
        float zr = ZZs[(2 * m) * 65 + 2 * ky]     - ZZs[(2 * m + 1) * 65 + 2 * ky + 1];
        float zi = ZZs[(2 * m) * 65 + 2 * ky + 1] + ZZs[(2 * m + 1) * 65 + 2 * ky];
        Z[(long)bi * 2048 + cid] = make_float2(zr, zi);
    }
}

// B: Zmix[b][o][m][ky] = sum_i Z[b][i][m][ky] * Wpack[m][ky][i][o].  bf16 wpack in, bf16 Zmix out.
__global__ void k_mix(const float2* __restrict__ Z, const unsigned* __restrict__ wpack,
                      unsigned* __restrict__ Zmixb) {
    __shared__ unsigned Ws[4][1024]; // 16 KB (bf16 complex)
    __shared__ float2 Zs[256][4];    // 8 KB  [bi][kk]
    __shared__ float2 Os[256][4];    // 8 KB  [bo][kk]
    int t = threadIdx.x;
    int mk0 = blockIdx.x * 4;
    {   // stage W: contiguous 16 KB
        const uint4* src = (const uint4*)(wpack + (long)mk0 * 1024);
        uint4* dst = (uint4*)&Ws[0][0];
        for (int j = t; j < 1024; j += BD) dst[j] = src[j];
    }
    for (int j = t; j < 512; j += BD) {   // stage Z: 32B per bi-row
        int bi = j >> 1, p = j & 1;
        *(float4*)&Zs[bi][p * 2] = *(const float4*)&Z[(long)bi * 2048 + mk0 + p * 2];
    }
    __syncthreads();
    int o = t & 31, kk = (t >> 5) & 3, bh = t >> 7;
    float ar[4], ai[4];
#pragma unroll
    for (int j = 0; j < 4; ++j) { ar[j] = 0.f; ai[j] = 0.f; }
    for (int i = 0; i < 32; ++i) {
        unsigned wu = Ws[kk][i * 32 + o];
        float wx = bf2f((unsigned short)wu);
        float wy = bf2f((unsigned short)(wu >> 16));
#pragma unroll
        for (int j = 0; j < 4; ++j) {
            float2 z = Zs[(bh * 4 + j) * 32 + i][kk];   // wave-broadcast
            ar[j] = fmaf(z.x, wx, fmaf(-z.y, wy, ar[j]));
            ai[j] = fmaf(z.x, wy, fmaf( z.y, wx, ai[j]));
        }
    }
#pragma unroll
    for (int j = 0; j < 4; ++j)
        Os[(bh * 4 + j) * 32 + o][kk] = make_float2(ar[j], ai[j]);
    __syncthreads();
    for (int j = t; j < 512; j += BD) {   // write bf16 complex: 2 complex = uint2 per j
        int row = j >> 1, p = j & 1;
        float2 a = Os[row][p * 2], b2 = Os[row][p * 2 + 1];
        uint2 u;
        u.x = (unsigned)f2bf(a.x)  | ((unsigned)f2bf(a.y)  << 16);
        u.y = (unsigned)f2bf(b2.x) | ((unsigned)f2bf(b2.y) << 16);
        *(uint2*)&Zmixb[(long)row * 2048 + mk0 + p * 2] = u;
    }
}

// Fused C (all-MFMA): block = (bo, h-half), 512 threads (8 waves).
// Phase 1: Bz[2ky+cc][2m+c] bf16 from bf16 Zmix; MFMA G[128 h1][64] = Th * Bz -> Gs bf16.
// Phase 2: C2 MFMA out[128 h][256 w] = Gs * BmC^T + bias.
__global__ __launch_bounds__(512) void k_fftC(const unsigned* __restrict__ Zmixb,
                                              const unsigned short* __restrict__ Th,
                                              const unsigned short* __restrict__ BmC,
                                              const float* __restrict__ bias,
                                              float* __restrict__ out) {
    __shared__ __align__(16) unsigned short Gs[128 * 72];   // 18432 B
    __shared__ __align__(16) char buf[128 * 72 * 2];        // 18432 B: Bz [64][136] / Bsh [128][72]
    unsigned short* Bz = (unsigned short*)buf;
    unsigned short* Bsh = (unsigned short*)buf;
    int t = threadIdx.x;
    int bo = blockIdx.x >> 1, hb = blockIdx.x & 1;
    {   // stage Bz: Bz[2ky][2m]=Zr, Bz[2ky][2m+1]=Zi, Bz[2ky+1][2m]=Zi, Bz[2ky+1][2m+1]=-Zr
#pragma unroll
        for (int p = 0; p < 4; ++p) {
            int cid = p * 512 + t;
            int m = cid >> 5, ky = cid & 31;
            unsigned z = Zmixb[(long)bo * 2048 + cid];
            unsigned short zr = (unsigned short)z;
            unsigned short zi = (unsigned short)(z >> 16);
            unsigned short nzr = zr ^ 0x8000;
            Bz[(2 * ky) * 136 + 2 * m]         = zr;
            Bz[(2 * ky) * 136 + 2 * m + 1]     = zi;
            Bz[(2 * ky + 1) * 136 + 2 * m]     = zi;
            Bz[(2 * ky + 1) * 136 + 2 * m + 1] = nzr;
        }
    }
    __syncthreads();
    int wv = t >> 6, lane = t & 63, lm = lane & 15, quad = lane >> 4;
    {   // GEMM1: G[h1][col] = sum_k2 Th[h][k2] * Bz[col][k2].  M=128, N=64, K=128.
        bf16x8 afr[4];
#pragma unroll
        for (int kk = 0; kk < 4; ++kk)
            afr[kk] = *(const bf16x8*)&Th[(hb * 128 + wv * 16 + lm) * 128 + kk * 32 + quad * 8];
        f32x4 ag[4] = {};
#pragma unroll
        for (int kk = 0; kk < 4; ++kk)
#pragma unroll
            for (int nt = 0; nt < 4; ++nt) {
                bf16x8 bf = *(const bf16x8*)&Bz[(nt * 16 + lm) * 136 + kk * 32 + quad * 8];
                ag[nt] = __builtin_amdgcn_mfma_f32_16x16x32_bf16(afr[kk], bf, ag[nt], 0, 0, 0);
            }
#pragma unroll
        for (int nt = 0; nt < 4; ++nt)
#pragma unroll
            for (int r = 0; r < 4; ++r)
                Gs[(wv * 16 + quad * 4 + r) * 72 + nt * 16 + lm] = f2bf(ag[nt][r]);
    }
    __syncthreads();   // Gs complete; Bz dead
    // C2: 8 waves x 16 rows; per phase p: N-half of 128 cols
    bf16x8 a0 = *(const bf16x8*)&Gs[(wv * 16 + lm) * 72 + quad * 8];
    bf16x8 a1 = *(const bf16x8*)&Gs[(wv * 16 + lm) * 72 + 32 + quad * 8];
    float bv = bias[bo & 31];
    long rowbase = (long)bo * 256 + hb * 128 + wv * 16;
    for (int p = 0; p < 2; ++p) {
        if (p) __syncthreads();   // all waves done reading Bsh phase 0
        {   // stage BmC half: rows p*128..p*128+128; 512 thr x 2 uint4 (16 shorts)
            int w = t >> 2, k0 = (t & 3) * 16;
            const uint4* src = (const uint4*)(BmC + (p * 128 + w) * 64 + k0);
            *(uint4*)&Bsh[w * 72 + k0]     = src[0];
            *(uint4*)&Bsh[w * 72 + k0 + 8] = src[1];
        }
        __syncthreads();
        f32x4 acc[8] = {};
#pragma unroll
        for (int nt = 0; nt < 8; ++nt) {
            bf16x8 b0 = *(const bf16x8*)&Bsh[(nt * 16 + lm) * 72 + quad * 8];
            bf16x8 b1 = *(const bf16x8*)&Bsh[(nt * 16 + lm) * 72 + 32 + quad * 8];
            acc[nt] = __builtin_amdgcn_mfma_f32_16x16x32_bf16(a0, b0, acc[nt], 0, 0, 0);
            acc[nt] = __builtin_amdgcn_mfma_f32_16x16x32_bf16(a1, b1, acc[nt], 0, 0, 0);
        }
#pragma unroll
        for (int nt = 0; nt < 8; ++nt)
#pragma unroll
            for (int r = 0; r < 4; ++r)
                out[(rowbase + quad * 4 + r) * 256 + p * 128 + nt * 16 + lm] = acc[nt][r] + bv;
    }
}

extern "C" void kernel_launch(void* const* d_in, const int* in_sizes, int n_in,
                              void* d_out, int out_size, void* d_ws, size_t ws_size,
                              hipStream_t stream) {
    const float* x    = (const float*)d_in[0];
    const float* w1r  = (const float*)d_in[1];
    const float* w1i  = (const float*)d_in[2];
    const float* w2r  = (const float*)d_in[3];
    const float* w2i  = (const float*)d_in[4];
    const float* bias = (const float*)d_in[5];

    char* ws = (char*)d_ws;
    float2* tw             = (float2*)(ws);                                  // 2 KB (slot 4KB)
    unsigned* wpack        = (unsigned*)(ws + 4096);                         // 8 MB (bf16 complex)
    unsigned short* BmA    = (unsigned short*)(ws + 4096 + (8l << 20));      // 32 KB
    unsigned short* BmC    = BmA + 64 * 256;                                 // 32 KB
    unsigned short* Tm     = (unsigned short*)(ws + 4096 + (8l << 20) + 65536);        // 64 KB
    unsigned short* Th     = Tm + 128 * 256;                                           // 64 KB
    float2* Z              = (float2*)(ws + 4096 + (8l << 20) + 65536 + 131072);       // 4 MB
    unsigned* Zmixb        = (unsigned*)((char*)Z + (4l << 20));             // 2 MB (bf16 complex)
    float* out             = (float*)d_out;

    k_setup <<<897, BD, 0, stream>>>(tw, BmA, BmC, Tm, Th, w1r, w1i, w2r, w2i, wpack);
    k_fftA  <<<256, 512, 0, stream>>>(x, BmA, Tm, Z);
    k_mix   <<<512, BD, 0, stream>>>(Z, wpack, Zmixb);
    k_fftC  <<<512, 512, 0, stream>>>(Zmixb, Th, BmC, bias, out);
}